// Round 10
// baseline (310.564 us; speedup 1.0000x reference)
//
#include <hip/hip_runtime.h>
#include <stdint.h>

#define NROW    8192
#define CDIM    256
#define NCODE   16384
#define MARGINF 6.0e-5f

typedef short short8 __attribute__((ext_vector_type(8)));
typedef float floatx4 __attribute__((ext_vector_type(4)));
typedef _Float16 half2v __attribute__((ext_vector_type(2)));

__device__ inline ushort f2bf(float f) {
    unsigned u = __builtin_bit_cast(unsigned, f);
    unsigned r = (u + 0x7fffu + ((u >> 16) & 1u)) >> 16;
    return (ushort)r;
}
__device__ inline unsigned fsort(float v) {
    unsigned u = __builtin_bit_cast(unsigned, v);
    return (u >> 31) ? ~u : (u | 0x80000000u);
}

__device__ inline void gl_lds16(const ushort* g, ushort* lds) {
    __builtin_amdgcn_global_load_lds(
        (const __attribute__((address_space(1))) unsigned int*)(g),
        (__attribute__((address_space(3))) unsigned int*)(lds),
        16, 0, 0);
}

// ---------------------------------------------------------------------------
// Fused prep: blocks 0..2047 = x transpose/convert; 2048..2175 = w bf16 + S2.
// Block 2048 thread 0 also zeroes the rescore completion counter.
// ---------------------------------------------------------------------------
__global__ __launch_bounds__(256) void prep_all(const float* __restrict__ x,
                                                const float* __restrict__ w,
                                                float* __restrict__ xf32,
                                                ushort* __restrict__ xbf,
                                                ushort* __restrict__ wbf,
                                                float* __restrict__ S2a,
                                                int* __restrict__ ctr) {
#pragma clang fp contract(off)
    const int bid = blockIdx.x;
    const int t = threadIdx.x;
    if (bid < 2048) {
        // ---- prep_x role: b = bid&7, ht = (bid>>3)&31, ct = bid>>8 ----
        __shared__ float tile[32][33];
        const int b = bid & 7, ht = (bid >> 3) & 31, ct = bid >> 8;
        const int hw0 = ht * 32, c0 = ct * 32;
        {
            const int cc = t >> 5, hh = t & 31;
            #pragma unroll
            for (int i = 0; i < 4; ++i) {
                int cl = cc + i * 8;
                tile[cl][hh] = x[((size_t)(b * 256 + c0 + cl) << 10) + hw0 + hh];
            }
        }
        __syncthreads();
        {
            const int col = t & 31, row = t >> 5;
            #pragma unroll
            for (int i = 0; i < 4; ++i) {
                int r = row + i * 8;
                float v = tile[col][r];
                size_t o = ((size_t)(b * 1024 + hw0 + r) << 8) + c0 + col;
                xf32[o] = v;
                xbf[o] = f2bf(v);
            }
        }
    } else {
        // ---- prep_w role: 2 threads per code j ----
        if (bid == 2048 && t == 0) *ctr = 0;
        const int gt = (bid - 2048) * 256 + t;
        const int j = gt >> 1, h = gt & 1;
        const float* a = w + ((size_t)j << 8) + h * 128;
        ushort* orow = wbf + ((size_t)j << 8) + h * 128;
        float r8[8];
        #pragma unroll
        for (int l = 0; l < 8; ++l) { float v = a[l]; r8[l] = v * v; }
        for (int i = 8; i < 128; i += 8) {
            #pragma unroll
            for (int l = 0; l < 8; ++l) { float v = a[i + l]; r8[l] = r8[l] + v * v; }
        }
        float hs = ((r8[0] + r8[1]) + (r8[2] + r8[3])) + ((r8[4] + r8[5]) + (r8[6] + r8[7]));
        float other = __shfl_xor(hs, 1);
        if (h == 0) S2a[j] = hs + other;   // fl(hs0 + hs1) — np order
        for (int i = 0; i < 128; i += 8) {
            ushort u8[8];
            #pragma unroll
            for (int l = 0; l < 8; ++l) u8[l] = f2bf(a[i + l]);
            *(ushort4*)(orow + i)     = make_ushort4(u8[0], u8[1], u8[2], u8[3]);
            *(ushort4*)(orow + i + 4) = make_ushort4(u8[4], u8[5], u8[6], u8[7]);
        }
    }
}

// ---------------------------------------------------------------------------
// bf16 MFMA GEMM with CODES on M, QUERIES on N (cheap in-lane epilogue).
// global_load_lds staging, XOR-swizzled LDS layout.
// Emits per (query row, 16-code block) min approx score as fp16:
//   bm16[n][1024], 16-block id jb = blockIdx.y*8 + wr*4 + mi.
// score = S2[j] - 2 * x.w  (S1 omitted: constant per row)
// ---------------------------------------------------------------------------
__global__ __launch_bounds__(256) void gemm_min(const ushort* __restrict__ Wb,
                                                const ushort* __restrict__ Xb,
                                                const float* __restrict__ S2a,
                                                ushort* __restrict__ bm16) {
    __shared__ __attribute__((aligned(16))) ushort As[8192];  // codes  [128][64] swz
    __shared__ __attribute__((aligned(16))) ushort Bs[8192];  // queries[128][64] swz
    __shared__ __attribute__((aligned(16))) ushort stg[128 * 8];

    const int n0 = blockIdx.x * 128;   // query block
    const int j0 = blockIdx.y * 128;   // code block
    const int t  = threadIdx.x;
    const int wv = t >> 6, l = t & 63;
    const int wr = wv >> 1, wc = wv & 1;   // wr: code 64-half, wc: query 64-half
    const int q  = l >> 4, c = l & 15;

    const int lr = l >> 3;
    const int lperm = (l & 7) ^ lr;
    const size_t gA0 = ((size_t)(j0 + wv * 32 + lr) << 8) + lperm * 8;
    const size_t gB0 = ((size_t)(n0 + wv * 32 + lr) << 8) + lperm * 8;
    const int ldsbase = wv * 2048;

    floatx4 acc[4][4];
    #pragma unroll
    for (int mi = 0; mi < 4; ++mi)
        #pragma unroll
        for (int ni = 0; ni < 4; ++ni)
            acc[mi][ni] = (floatx4){0.f, 0.f, 0.f, 0.f};

    for (int kb = 0; kb < 4; ++kb) {
        if (kb) __syncthreads();
        #pragma unroll
        for (int ca = 0; ca < 4; ++ca) {
            gl_lds16(Wb + gA0 + ca * 2048 + kb * 64, As + ldsbase + ca * 512);
            gl_lds16(Xb + gB0 + ca * 2048 + kb * 64, Bs + ldsbase + ca * 512);
        }
        __syncthreads();
        #pragma unroll
        for (int kk = 0; kk < 2; ++kk) {
            short8 af[4], bf[4];
            #pragma unroll
            for (int mi = 0; mi < 4; ++mi) {
                int row = wr * 64 + mi * 16 + c;
                int pos = (kk * 4 + q) ^ (c & 7);
                af[mi] = *(const short8*)&As[row * 64 + pos * 8];
            }
            #pragma unroll
            for (int ni = 0; ni < 4; ++ni) {
                int row = wc * 64 + ni * 16 + c;
                int pos = (kk * 4 + q) ^ (c & 7);
                bf[ni] = *(const short8*)&Bs[row * 64 + pos * 8];
            }
            #pragma unroll
            for (int mi = 0; mi < 4; ++mi)
                #pragma unroll
                for (int ni = 0; ni < 4; ++ni)
                    acc[mi][ni] = __builtin_amdgcn_mfma_f32_16x16x32_bf16(
                        af[mi], bf[ni], acc[mi][ni], 0, 0, 0);
        }
    }

    // Epilogue: D rows = codes (q*4+r), cols = queries (c).
    #pragma unroll
    for (int mi = 0; mi < 4; ++mi) {
        float4 s2 = *(const float4*)&S2a[j0 + wr * 64 + mi * 16 + (q << 2)];
        #pragma unroll
        for (int ni = 0; ni < 4; ++ni) {
            float m0 = fmaf(-2.f, acc[mi][ni][0], s2.x);
            float m1 = fmaf(-2.f, acc[mi][ni][1], s2.y);
            float m2 = fmaf(-2.f, acc[mi][ni][2], s2.z);
            float m3 = fmaf(-2.f, acc[mi][ni][3], s2.w);
            float m = fminf(fminf(m0, m1), fminf(m2, m3));
            m = fminf(m, __shfl_xor(m, 16));
            m = fminf(m, __shfl_xor(m, 32));
            if (q == 0) {
                int qr = wc * 64 + ni * 16 + c;        // query row in block
                stg[qr * 8 + wr * 4 + mi] =
                    __builtin_bit_cast(ushort, (_Float16)m);
            }
        }
    }
    __syncthreads();
    if (t < 128) {
        uint4 v = *(const uint4*)&stg[t * 8];
        *(uint4*)(bm16 + ((size_t)(n0 + t) << 10) + blockIdx.y * 8) = v;
    }
}

// ---------------------------------------------------------------------------
// ONE WAVE PER ROW. Candidate prune + exact np-fp32 rescore (one candidate
// code per lane, register-batched loads). FUSED OUTPUTS: each lane writes its
// w[J] float4 to the transposed xq_img positions; loss via per-block partials
// + last-block deterministic reduction (counter zeroed in prep_all).
// ---------------------------------------------------------------------------
__global__ __launch_bounds__(256) void rescore6(const ushort* __restrict__ bm16,
                                                const float* __restrict__ xf32,
                                                const float* __restrict__ w,
                                                const float* __restrict__ S2a,
                                                float* __restrict__ out,
                                                float* __restrict__ xcode,
                                                float* __restrict__ lpart,
                                                int* __restrict__ ctr,
                                                float* __restrict__ loss) {
#pragma clang fp contract(off)
    __shared__ float xs[4][256];
    __shared__ short list[4][128];
    __shared__ int ncand[4];
    __shared__ float wp[4];
    __shared__ int is_last;

    const int t = threadIdx.x, wv = t >> 6, l = t & 63;
    const int n = blockIdx.x * 4 + wv;
    if (l == 0) ncand[wv] = 0;

    // stage xrow (coalesced float4/lane)
    const float4 xv = *(const float4*)&xf32[((size_t)n << 8) + l * 4];
    *(float4*)&xs[wv][l * 4] = xv;

    // bm16 row: lane l covers blocks l*16 .. l*16+15 (32 B/lane, coalesced)
    const uint4* bp = (const uint4*)(bm16 + ((size_t)n << 10) + l * 16);
    const uint4 b0 = bp[0], b1 = bp[1];
    float vals[16];
    {
        unsigned uu[8] = {b0.x, b0.y, b0.z, b0.w, b1.x, b1.y, b1.z, b1.w};
        #pragma unroll
        for (int i = 0; i < 8; ++i) {
            half2v h = __builtin_bit_cast(half2v, uu[i]);
            vals[2 * i]     = (float)h[0];
            vals[2 * i + 1] = (float)h[1];
        }
    }
    float vmin = vals[0];
    #pragma unroll
    for (int i = 1; i < 16; ++i) vmin = fminf(vmin, vals[i]);
    #pragma unroll
    for (int off = 1; off <= 32; off <<= 1) vmin = fminf(vmin, __shfl_xor(vmin, off));
    const float thr = vmin + MARGINF;
    #pragma unroll
    for (int i = 0; i < 16; ++i)
        if (vals[i] <= thr) {
            int p = atomicAdd(&ncand[wv], 1);
            if (p < 128) list[wv][p] = (short)(l * 16 + i);
        }

    // exact np pairwise S1: lanes 0..15 (half h = l>>3, accumulator a = l&7)
    float racc = 0.f;
    if (l < 16) {
        const float* a_ = &xs[wv][(l >> 3) * 128];
        const int ai = l & 7;
        float v = a_[ai];
        racc = v * v;
        for (int i = 8; i < 128; i += 8) { v = a_[i + ai]; racc = racc + v * v; }
    }
    // butterfly reproduces ((r0+r1)+(r2+r3))+((r4+r5)+(r6+r7)), then hs0+hs1
    racc = racc + __shfl_xor(racc, 1);
    racc = racc + __shfl_xor(racc, 2);
    racc = racc + __shfl_xor(racc, 4);
    racc = racc + __shfl_xor(racc, 8);   // lane 0: hs0 + hs1 (np order)
    const float S1n = __shfl(racc, 0);

    // one candidate code per lane, register-batched w loads (MLP ~16)
    const int ntot = (ncand[wv] < 128 ? ncand[wv] : 128) * 16;
    unsigned long long best = ~0ull;
    for (int s = l; s < ntot; s += 64) {
        const int j = (int)list[wv][s >> 4] * 16 + (s & 15);
        const float4* wr4 = (const float4*)(w + ((size_t)j << 8));
        float g = 0.f;
        #pragma unroll
        for (int half = 0; half < 4; ++half) {
            float4 buf[16];
            #pragma unroll
            for (int i = 0; i < 16; ++i) buf[i] = wr4[half * 16 + i];  // 16 indep loads
            #pragma unroll
            for (int i = 0; i < 16; ++i) {   // sequential FMA in k-order (BLAS)
                const float4 xv4 = *(const float4*)&xs[wv][half * 64 + i * 4];
                g = fmaf(xv4.x, buf[i].x, g);
                g = fmaf(xv4.y, buf[i].y, g);
                g = fmaf(xv4.z, buf[i].z, g);
                g = fmaf(xv4.w, buf[i].w, g);
            }
        }
        float d = (S1n + S2a[j]) - 2.0f * g;
        unsigned long long key = ((unsigned long long)fsort(d) << 32) | (unsigned)j;
        if (key < best) best = key;
    }
    #pragma unroll
    for (int off = 1; off <= 32; off <<= 1) {
        unsigned long long o = __shfl_xor(best, off);
        if (o < best) best = o;
    }
    const int J = (int)(best & 0xffffffffu);
    if (l == 0) xcode[n] = (float)J;

    // gather w[J] float4 per lane; write transposed xq_img + loss partial
    const float4 wj = *(const float4*)&w[((size_t)J << 8) + l * 4];
    {
        float* ob = out + ((size_t)(n >> 10) << 18) + ((size_t)l << 12) + (n & 1023);
        ob[0]    = wj.x;
        ob[1024] = wj.y;
        ob[2048] = wj.z;
        ob[3072] = wj.w;
    }
    float d0 = wj.x - xv.x, d1 = wj.y - xv.y, d2 = wj.z - xv.z, d3 = wj.w - xv.w;
    float lacc = (d0 * d0 + d1 * d1) + (d2 * d2 + d3 * d3);
    #pragma unroll
    for (int off = 1; off <= 32; off <<= 1) lacc += __shfl_xor(lacc, off);
    if (l == 0) wp[wv] = lacc;
    __syncthreads();
    if (t == 0) {
        lpart[blockIdx.x] = (wp[0] + wp[1]) + (wp[2] + wp[3]);
        __threadfence();
        int old = atomicAdd(ctr, 1);
        is_last = (old == (int)gridDim.x - 1) ? 1 : 0;
    }
    __syncthreads();
    if (is_last) {
        __threadfence();
        __shared__ float red[256];
        float s = 0.f;
        for (int i = t; i < 2048; i += 256) s += lpart[i];  // fixed mapping
        red[t] = s;
        __syncthreads();
        for (int k = 128; k > 0; k >>= 1) {
            if (t < k) red[t] += red[t + k];
            __syncthreads();
        }
        if (t == 0) *loss = red[0] * (1.25f / 2097152.0f);
    }
}

// ---------------------------------------------------------------------------
extern "C" void kernel_launch(void* const* d_in, const int* in_sizes, int n_in,
                              void* d_out, int out_size, void* d_ws, size_t ws_size,
                              hipStream_t stream) {
    const float* x = (const float*)d_in[0];
    const float* w = (const float*)d_in[1];
    float* out = (float*)d_out;

    char* ws = (char*)d_ws;
    const size_t MB = 1024u * 1024u;
    ushort* xbf   = (ushort*)(ws);                   //  4 MiB
    float*  xf32  = (float*) (ws + 4 * MB);          //  8 MiB
    ushort* wbf   = (ushort*)(ws + 12 * MB);         //  8 MiB
    float*  S2a   = (float*) (ws + 20 * MB);         // 64 KiB
    ushort* bm16  = (ushort*)(ws + 21 * MB);         // 16 MiB
    float*  lpart = (float*) (ws + 37 * MB);         //  8 KiB
    int*    ctr   = (int*)   (ws + 37 * MB + 16384); //  4 B

    float* loss_ptr  = out + 2097152;
    float* xcode_ptr = out + 2097153;

    prep_all<<<dim3(2176),     256, 0, stream>>>(x, w, xf32, xbf, wbf, S2a, ctr);
    gemm_min<<<dim3(64, 128),  256, 0, stream>>>(wbf, xbf, S2a, bm16);
    rescore6<<<dim3(2048),     256, 0, stream>>>(bm16, xf32, w, S2a, out,
                                                 xcode_ptr, lpart, ctr, loss_ptr);
}

// Round 11
// 286.444 us; speedup vs baseline: 1.0842x; 1.0842x over previous
//
#include <hip/hip_runtime.h>
#include <stdint.h>

#define NROW    8192
#define CDIM    256
#define NCODE   16384
#define MARGINF 6.0e-5f

typedef short short8 __attribute__((ext_vector_type(8)));
typedef float floatx4 __attribute__((ext_vector_type(4)));

__device__ inline ushort f2bf(float f) {
    unsigned u = __builtin_bit_cast(unsigned, f);
    unsigned r = (u + 0x7fffu + ((u >> 16) & 1u)) >> 16;
    return (ushort)r;
}
__device__ inline unsigned fsort(float v) {
    unsigned u = __builtin_bit_cast(unsigned, v);
    return (u >> 31) ? ~u : (u | 0x80000000u);
}

__device__ inline void gl_lds16(const ushort* g, ushort* lds) {
    __builtin_amdgcn_global_load_lds(
        (const __attribute__((address_space(1))) unsigned int*)(g),
        (__attribute__((address_space(3))) unsigned int*)(lds),
        16, 0, 0);
}

// ---------------------------------------------------------------------------
// Fused prep: blocks 0..2047 = x transpose/convert; 2048..2175 = w bf16 + S2.
// ---------------------------------------------------------------------------
__global__ __launch_bounds__(256) void prep_all(const float* __restrict__ x,
                                                const float* __restrict__ w,
                                                float* __restrict__ xf32,
                                                ushort* __restrict__ xbf,
                                                ushort* __restrict__ wbf,
                                                float* __restrict__ S2a) {
#pragma clang fp contract(off)
    const int bid = blockIdx.x;
    const int t = threadIdx.x;
    if (bid < 2048) {
        __shared__ float tile[32][33];
        const int b = bid & 7, ht = (bid >> 3) & 31, ct = bid >> 8;
        const int hw0 = ht * 32, c0 = ct * 32;
        {
            const int cc = t >> 5, hh = t & 31;
            #pragma unroll
            for (int i = 0; i < 4; ++i) {
                int cl = cc + i * 8;
                tile[cl][hh] = x[((size_t)(b * 256 + c0 + cl) << 10) + hw0 + hh];
            }
        }
        __syncthreads();
        {
            const int col = t & 31, row = t >> 5;
            #pragma unroll
            for (int i = 0; i < 4; ++i) {
                int r = row + i * 8;
                float v = tile[col][r];
                size_t o = ((size_t)(b * 1024 + hw0 + r) << 8) + c0 + col;
                xf32[o] = v;
                xbf[o] = f2bf(v);
            }
        }
    } else {
        const int gt = (bid - 2048) * 256 + t;
        const int j = gt >> 1, h = gt & 1;
        const float* a = w + ((size_t)j << 8) + h * 128;
        ushort* orow = wbf + ((size_t)j << 8) + h * 128;
        float r8[8];
        #pragma unroll
        for (int l = 0; l < 8; ++l) { float v = a[l]; r8[l] = v * v; }
        for (int i = 8; i < 128; i += 8) {
            #pragma unroll
            for (int l = 0; l < 8; ++l) { float v = a[i + l]; r8[l] = r8[l] + v * v; }
        }
        float hs = ((r8[0] + r8[1]) + (r8[2] + r8[3])) + ((r8[4] + r8[5]) + (r8[6] + r8[7]));
        float other = __shfl_xor(hs, 1);
        if (h == 0) S2a[j] = hs + other;   // fl(hs0 + hs1) — np order
        for (int i = 0; i < 128; i += 8) {
            ushort u8[8];
            #pragma unroll
            for (int l = 0; l < 8; ++l) u8[l] = f2bf(a[i + l]);
            *(ushort4*)(orow + i)     = make_ushort4(u8[0], u8[1], u8[2], u8[3]);
            *(ushort4*)(orow + i + 4) = make_ushort4(u8[4], u8[5], u8[6], u8[7]);
        }
    }
}

// ---------------------------------------------------------------------------
// bf16 MFMA GEMM, codes on M / queries on N. Per (query, 16-code block) emits
// packed u32:  [min fp16 | second-minus-min delta (fp16 top-8, trunc-DOWN) |
// argmin idx4].  Conservative delta => rescore candidate set is a superset of
// all codes within margin.  bm32[n][1024], block id = blockIdx.y*8 + wr*4 + mi.
// ---------------------------------------------------------------------------
__global__ __launch_bounds__(256) void gemm_min(const ushort* __restrict__ Wb,
                                                const ushort* __restrict__ Xb,
                                                const float* __restrict__ S2a,
                                                unsigned* __restrict__ bm32) {
    __shared__ __attribute__((aligned(16))) ushort As[8192];  // codes  [128][64] swz
    __shared__ __attribute__((aligned(16))) ushort Bs[8192];  // queries[128][64] swz
    __shared__ __attribute__((aligned(16))) unsigned stg32[128][8];

    const int n0 = blockIdx.x * 128;   // query block
    const int j0 = blockIdx.y * 128;   // code block
    const int t  = threadIdx.x;
    const int wv = t >> 6, l = t & 63;
    const int wr = wv >> 1, wc = wv & 1;
    const int q  = l >> 4, c = l & 15;

    const int lr = l >> 3;
    const int lperm = (l & 7) ^ lr;
    const size_t gA0 = ((size_t)(j0 + wv * 32 + lr) << 8) + lperm * 8;
    const size_t gB0 = ((size_t)(n0 + wv * 32 + lr) << 8) + lperm * 8;
    const int ldsbase = wv * 2048;

    floatx4 acc[4][4];
    #pragma unroll
    for (int mi = 0; mi < 4; ++mi)
        #pragma unroll
        for (int ni = 0; ni < 4; ++ni)
            acc[mi][ni] = (floatx4){0.f, 0.f, 0.f, 0.f};

    for (int kb = 0; kb < 4; ++kb) {
        if (kb) __syncthreads();
        #pragma unroll
        for (int ca = 0; ca < 4; ++ca) {
            gl_lds16(Wb + gA0 + ca * 2048 + kb * 64, As + ldsbase + ca * 512);
            gl_lds16(Xb + gB0 + ca * 2048 + kb * 64, Bs + ldsbase + ca * 512);
        }
        __syncthreads();
        #pragma unroll
        for (int kk = 0; kk < 2; ++kk) {
            short8 af[4], bf[4];
            #pragma unroll
            for (int mi = 0; mi < 4; ++mi) {
                int row = wr * 64 + mi * 16 + c;
                int pos = (kk * 4 + q) ^ (c & 7);
                af[mi] = *(const short8*)&As[row * 64 + pos * 8];
            }
            #pragma unroll
            for (int ni = 0; ni < 4; ++ni) {
                int row = wc * 64 + ni * 16 + c;
                int pos = (kk * 4 + q) ^ (c & 7);
                bf[ni] = *(const short8*)&Bs[row * 64 + pos * 8];
            }
            #pragma unroll
            for (int mi = 0; mi < 4; ++mi)
                #pragma unroll
                for (int ni = 0; ni < 4; ++ni)
                    acc[mi][ni] = __builtin_amdgcn_mfma_f32_16x16x32_bf16(
                        af[mi], bf[ni], acc[mi][ni], 0, 0, 0);
        }
    }

    // Epilogue: D rows = codes (q*4+r), cols = queries (c).
    // Per (mi,ni): top-2 + argmin over 16 codes (4 in-lane regs x 4 quads).
    #pragma unroll
    for (int mi = 0; mi < 4; ++mi) {
        float4 s2 = *(const float4*)&S2a[j0 + wr * 64 + mi * 16 + (q << 2)];
        #pragma unroll
        for (int ni = 0; ni < 4; ++ni) {
            float v0 = fmaf(-2.f, acc[mi][ni][0], s2.x);
            float v1 = fmaf(-2.f, acc[mi][ni][1], s2.y);
            float v2 = fmaf(-2.f, acc[mi][ni][2], s2.z);
            float v3 = fmaf(-2.f, acc[mi][ni][3], s2.w);
            float lo01 = fminf(v0, v1), hi01 = fmaxf(v0, v1);
            float lo23 = fminf(v2, v3), hi23 = fmaxf(v2, v3);
            int   i01 = v1 < v0 ? 1 : 0;
            int   i23 = v3 < v2 ? 3 : 2;
            float m1 = fminf(lo01, lo23);
            float m2 = fminf(fmaxf(lo01, lo23), lo23 < lo01 ? hi23 : hi01);
            int   i1 = (q << 2) | (lo23 < lo01 ? i23 : i01);
            #pragma unroll
            for (int off = 16; off <= 32; off <<= 1) {
                float om1 = __shfl_xor(m1, off);
                float om2 = __shfl_xor(m2, off);
                int   oi1 = __shfl_xor(i1, off);
                float nm2 = fminf(fminf(m2, om2), fmaxf(m1, om1));
                i1 = om1 < m1 ? oi1 : i1;
                m1 = fminf(m1, om1);
                m2 = nm2;
            }
            if (q == 0) {
                ushort min16 = __builtin_bit_cast(ushort, (_Float16)m1);
                float delta = m2 - m1;
                ushort d16 = __builtin_bit_cast(ushort, (_Float16)delta);
                ushort d8 = d16 >> 8;
                float rec = (float)__builtin_bit_cast(_Float16, (ushort)(d8 << 8));
                if (rec > delta && d8) d8--;   // stored delta must be <= actual
                stg32[wc * 64 + ni * 16 + c][wr * 4 + mi] =
                    ((unsigned)min16 << 16) | ((unsigned)d8 << 8) | (unsigned)i1;
            }
        }
    }
    __syncthreads();
    if (t < 128) {
        uint4 a0 = *(const uint4*)&stg32[t][0];
        uint4 a1 = *(const uint4*)&stg32[t][4];
        size_t base = ((size_t)(n0 + t) << 10) + blockIdx.y * 8;
        *(uint4*)(bm32 + base)     = a0;
        *(uint4*)(bm32 + base + 4) = a1;
    }
}

// ---------------------------------------------------------------------------
// ONE WAVE PER ROW. Scan 1024 packed block entries; candidates = argmin of
// blocks with min<=thr, plus full 16 codes of blocks with min+delta<=thr
// (conservative superset).  Exact np-fp32 sequential k-order FMA rescore of
// candidates (one per lane, register-batched loads).  Loss partial per row.
// ---------------------------------------------------------------------------
__global__ __launch_bounds__(256) void rescore7(const unsigned* __restrict__ bm32,
                                                const float* __restrict__ xf32,
                                                const float* __restrict__ w,
                                                const float* __restrict__ S2a,
                                                int* __restrict__ idxb,
                                                float* __restrict__ xcode,
                                                float* __restrict__ lpart) {
#pragma clang fp contract(off)
    __shared__ float xs[4][256];
    __shared__ short sing[4][128];
    __shared__ short blk[4][32];
    __shared__ int ns[4], nb[4];

    const int t = threadIdx.x, wv = t >> 6, l = t & 63;
    const int n = blockIdx.x * 4 + wv;
    if (l == 0) { ns[wv] = 0; nb[wv] = 0; }

    const float4 xv = *(const float4*)&xf32[((size_t)n << 8) + l * 4];
    *(float4*)&xs[wv][l * 4] = xv;

    // lane l covers block entries l*16 .. l*16+15 (64 B contiguous)
    const unsigned* bp = bm32 + ((size_t)n << 10) + l * 16;
    unsigned ee[16];
    {
        uint4 e0 = *(const uint4*)(bp);
        uint4 e1 = *(const uint4*)(bp + 4);
        uint4 e2 = *(const uint4*)(bp + 8);
        uint4 e3 = *(const uint4*)(bp + 12);
        ee[0]=e0.x; ee[1]=e0.y; ee[2]=e0.z; ee[3]=e0.w;
        ee[4]=e1.x; ee[5]=e1.y; ee[6]=e1.z; ee[7]=e1.w;
        ee[8]=e2.x; ee[9]=e2.y; ee[10]=e2.z; ee[11]=e2.w;
        ee[12]=e3.x; ee[13]=e3.y; ee[14]=e3.z; ee[15]=e3.w;
    }
    float vals[16];
    #pragma unroll
    for (int i = 0; i < 16; ++i)
        vals[i] = (float)__builtin_bit_cast(_Float16, (ushort)(ee[i] >> 16));
    float vmin = vals[0];
    #pragma unroll
    for (int i = 1; i < 16; ++i) vmin = fminf(vmin, vals[i]);
    #pragma unroll
    for (int off = 1; off <= 32; off <<= 1) vmin = fminf(vmin, __shfl_xor(vmin, off));
    const float thr = vmin + MARGINF;
    #pragma unroll
    for (int i = 0; i < 16; ++i) {
        if (vals[i] <= thr) {
            const int jb = l * 16 + i;
            int p = atomicAdd(&ns[wv], 1);
            if (p < 128) sing[wv][p] = (short)(jb * 16 + (int)(ee[i] & 15u));
            float dr = (float)__builtin_bit_cast(_Float16,
                           (ushort)(((ee[i] >> 8) & 0xFFu) << 8));
            if (vals[i] + dr <= thr) {
                int pb = atomicAdd(&nb[wv], 1);
                if (pb < 32) blk[wv][pb] = (short)jb;
            }
        }
    }

    // exact np pairwise S1: lanes 0..15 (half h = l>>3, accumulator a = l&7)
    float racc = 0.f;
    if (l < 16) {
        const float* a_ = &xs[wv][(l >> 3) * 128];
        const int ai = l & 7;
        float v = a_[ai];
        racc = v * v;
        for (int i = 8; i < 128; i += 8) { v = a_[i + ai]; racc = racc + v * v; }
    }
    racc = racc + __shfl_xor(racc, 1);
    racc = racc + __shfl_xor(racc, 2);
    racc = racc + __shfl_xor(racc, 4);
    racc = racc + __shfl_xor(racc, 8);   // lane 0: hs0 + hs1 (np order)
    const float S1n = __shfl(racc, 0);

    const int nsv = ns[wv] < 128 ? ns[wv] : 128;
    const int nbv = nb[wv] < 32 ? nb[wv] : 32;
    const int ntot = nsv + nbv * 16;
    unsigned long long best = ~0ull;
    for (int s = l; s < ntot; s += 64) {
        const int j = (s < nsv)
            ? (int)sing[wv][s]
            : (int)blk[wv][(s - nsv) >> 4] * 16 + ((s - nsv) & 15);
        const float4* wr4 = (const float4*)(w + ((size_t)j << 8));
        float g = 0.f;
        #pragma unroll
        for (int half = 0; half < 4; ++half) {
            float4 buf[16];
            #pragma unroll
            for (int i = 0; i < 16; ++i) buf[i] = wr4[half * 16 + i];
            #pragma unroll
            for (int i = 0; i < 16; ++i) {   // sequential FMA in k-order (BLAS)
                const float4 xv4 = *(const float4*)&xs[wv][half * 64 + i * 4];
                g = fmaf(xv4.x, buf[i].x, g);
                g = fmaf(xv4.y, buf[i].y, g);
                g = fmaf(xv4.z, buf[i].z, g);
                g = fmaf(xv4.w, buf[i].w, g);
            }
        }
        float d = (S1n + S2a[j]) - 2.0f * g;
        unsigned long long key = ((unsigned long long)fsort(d) << 32) | (unsigned)j;
        if (key < best) best = key;
    }
    #pragma unroll
    for (int off = 1; off <= 32; off <<= 1) {
        unsigned long long o = __shfl_xor(best, off);
        if (o < best) best = o;
    }
    const int J = (int)(best & 0xffffffffu);

    // loss partial for this row (w[J] L2-hot from the dot)
    const float4 wj = *(const float4*)&w[((size_t)J << 8) + l * 4];
    float d0 = wj.x - xv.x, d1 = wj.y - xv.y, d2 = wj.z - xv.z, d3 = wj.w - xv.w;
    float lacc = (d0 * d0 + d1 * d1) + (d2 * d2 + d3 * d3);
    #pragma unroll
    for (int off = 1; off <= 32; off <<= 1) lacc += __shfl_xor(lacc, off);
    if (l == 0) {
        idxb[n] = J;
        xcode[n] = (float)J;
        lpart[n] = lacc;
    }
}

// ---------------------------------------------------------------------------
// xq_img gather (coalesced); block (0,0,0) also reduces loss partials.
// ---------------------------------------------------------------------------
__global__ __launch_bounds__(256) void outputs_k(const float* __restrict__ w,
                                                 const int* __restrict__ idxb,
                                                 const float* __restrict__ lpart,
                                                 float* __restrict__ out,
                                                 float* __restrict__ loss) {
    const int b = blockIdx.x, hq = blockIdx.y, cs = blockIdx.z;
    const int t = threadIdx.x;
    const int hw = hq * 256 + t;
    const int n = (b << 10) + hw;
    const int id = idxb[n];
    #pragma unroll 4
    for (int ci = 0; ci < 32; ++ci) {
        const int c_ = cs * 32 + ci;
        const size_t oo = ((size_t)((b << 8) + c_) << 10) + hw;
        out[oo] = w[((size_t)id << 8) + c_];
    }
    if (b == 0 && hq == 0 && cs == 0) {
        __shared__ float red[256];
        float s = 0.f;
        for (int i = 0; i < 32; ++i) s += lpart[t + (i << 8)];
        red[t] = s;
        __syncthreads();
        for (int k = 128; k > 0; k >>= 1) {
            if (t < k) red[t] += red[t + k];
            __syncthreads();
        }
        if (t == 0) *loss = red[0] * (1.25f / 2097152.0f);
    }
}

// ---------------------------------------------------------------------------
extern "C" void kernel_launch(void* const* d_in, const int* in_sizes, int n_in,
                              void* d_out, int out_size, void* d_ws, size_t ws_size,
                              hipStream_t stream) {
    const float* x = (const float*)d_in[0];
    const float* w = (const float*)d_in[1];
    float* out = (float*)d_out;

    char* ws = (char*)d_ws;
    const size_t MB = 1024u * 1024u;
    ushort*   xbf   = (ushort*)  (ws);                   //  4 MiB
    float*    xf32  = (float*)   (ws + 4 * MB);          //  8 MiB
    ushort*   wbf   = (ushort*)  (ws + 12 * MB);         //  8 MiB
    float*    S2a   = (float*)   (ws + 20 * MB);         // 64 KiB
    unsigned* bm32  = (unsigned*)(ws + 21 * MB);         // 32 MiB
    int*      idxb  = (int*)     (ws + 53 * MB);         // 32 KiB
    float*    lpart = (float*)   (ws + 53 * MB + 65536); // 32 KiB

    float* loss_ptr  = out + 2097152;
    float* xcode_ptr = out + 2097153;

    prep_all<<<dim3(2176),     256, 0, stream>>>(x, w, xf32, xbf, wbf, S2a);
    gemm_min<<<dim3(64, 128),  256, 0, stream>>>(wbf, xbf, S2a, bm32);
    rescore7<<<dim3(2048),     256, 0, stream>>>(bm32, xf32, w, S2a, idxb,
                                                 xcode_ptr, lpart);
    outputs_k<<<dim3(8, 4, 8), 256, 0, stream>>>(w, idxb, lpart, out, loss_ptr);
}

// Round 12
// 248.623 us; speedup vs baseline: 1.2491x; 1.1521x over previous
//
#include <hip/hip_runtime.h>
#include <stdint.h>

#define NROW    8192
#define CDIM    256
#define NCODE   16384
#define MARGINF 6.0e-5f

typedef short short8 __attribute__((ext_vector_type(8)));
typedef float floatx4 __attribute__((ext_vector_type(4)));

__device__ inline ushort f2bf(float f) {
    unsigned u = __builtin_bit_cast(unsigned, f);
    unsigned r = (u + 0x7fffu + ((u >> 16) & 1u)) >> 16;
    return (ushort)r;
}
__device__ inline unsigned fsort(float v) {
    unsigned u = __builtin_bit_cast(unsigned, v);
    return (u >> 31) ? ~u : (u | 0x80000000u);
}

__device__ inline void gl_lds16(const ushort* g, ushort* lds) {
    __builtin_amdgcn_global_load_lds(
        (const __attribute__((address_space(1))) unsigned int*)(g),
        (__attribute__((address_space(3))) unsigned int*)(lds),
        16, 0, 0);
}

// ---------------------------------------------------------------------------
// Fused prep: blocks 0..2047 = x transpose/convert (32x32 LDS tiles);
// blocks 2048..3071 = w bf16 + exact np-pairwise S2 (16 threads per code row,
// butterfly reproduces ((r0+r1)+(r2+r3))+((r4+r5)+(r6+r7)) then hs0+hs1).
// ---------------------------------------------------------------------------
__global__ __launch_bounds__(256) void prep_all(const float* __restrict__ x,
                                                const float* __restrict__ w,
                                                float* __restrict__ xf32,
                                                ushort* __restrict__ xbf,
                                                ushort* __restrict__ wbf,
                                                float* __restrict__ S2a) {
#pragma clang fp contract(off)
    const int bid = blockIdx.x;
    const int t = threadIdx.x;
    if (bid < 2048) {
        __shared__ float tile[32][33];
        const int b = bid & 7, ht = (bid >> 3) & 31, ct = bid >> 8;
        const int hw0 = ht * 32, c0 = ct * 32;
        {
            const int cc = t >> 5, hh = t & 31;
            #pragma unroll
            for (int i = 0; i < 4; ++i) {
                int cl = cc + i * 8;
                tile[cl][hh] = x[((size_t)(b * 256 + c0 + cl) << 10) + hw0 + hh];
            }
        }
        __syncthreads();
        {
            const int col = t & 31, row = t >> 5;
            #pragma unroll
            for (int i = 0; i < 4; ++i) {
                int r = row + i * 8;
                float v = tile[col][r];
                size_t o = ((size_t)(b * 1024 + hw0 + r) << 8) + c0 + col;
                xf32[o] = v;
                xbf[o] = f2bf(v);
            }
        }
    } else {
        // 16 threads per code row j
        const int gt = (bid - 2048) * 256 + t;
        const int j = gt >> 4, l16 = gt & 15;
        const int h = l16 >> 3, ai = l16 & 7;
        const float* a = w + ((size_t)j << 8);
        // np 8-accumulator sequential partial (elements ai, ai+8, ..., ai+120)
        float v = a[h * 128 + ai];
        float racc = v * v;
        for (int i = 8; i < 128; i += 8) {
            v = a[h * 128 + ai + i];
            racc = racc + v * v;
        }
        racc = racc + __shfl_xor(racc, 1);
        racc = racc + __shfl_xor(racc, 2);
        racc = racc + __shfl_xor(racc, 4);   // lane ai==0: full bracket per half
        racc = racc + __shfl_xor(racc, 8);   // lane l16==0: hs0 + hs1 (np order)
        if (l16 == 0) S2a[j] = racc;
        // bf16 conversion: contiguous 16-elem segment per thread
        const float* seg = a + l16 * 16;
        ushort* oseg = wbf + ((size_t)j << 8) + l16 * 16;
        #pragma unroll
        for (int i = 0; i < 16; i += 8) {
            ushort u8[8];
            #pragma unroll
            for (int k = 0; k < 8; ++k) u8[k] = f2bf(seg[i + k]);
            *(ushort4*)(oseg + i)     = make_ushort4(u8[0], u8[1], u8[2], u8[3]);
            *(ushort4*)(oseg + i + 4) = make_ushort4(u8[4], u8[5], u8[6], u8[7]);
        }
    }
}

// ---------------------------------------------------------------------------
// bf16 MFMA GEMM, codes on M / queries on N. Per (query, 64-code group) one
// packed u32: [min fp16 | (second-min)-min delta fp16-top8 trunc-DOWN | idx6].
// In-lane merge over the 4 mi tiles (no shfl), then one 2-level quad merge
// per ni with explicit first-index tie-break. bm32[n][256],
// group id = blockIdx.y*2 + wr.
// ---------------------------------------------------------------------------
__global__ __launch_bounds__(256) void gemm_min(const ushort* __restrict__ Wb,
                                                const ushort* __restrict__ Xb,
                                                const float* __restrict__ S2a,
                                                unsigned* __restrict__ bm32) {
    __shared__ __attribute__((aligned(16))) ushort As[8192];  // codes  [128][64] swz
    __shared__ __attribute__((aligned(16))) ushort Bs[8192];  // queries[128][64] swz
    __shared__ __attribute__((aligned(16))) unsigned stg32[128][2];

    const int n0 = blockIdx.x * 128;   // query block
    const int j0 = blockIdx.y * 128;   // code block
    const int t  = threadIdx.x;
    const int wv = t >> 6, l = t & 63;
    const int wr = wv >> 1, wc = wv & 1;
    const int q  = l >> 4, c = l & 15;

    const int lr = l >> 3;
    const int lperm = (l & 7) ^ lr;
    const size_t gA0 = ((size_t)(j0 + wv * 32 + lr) << 8) + lperm * 8;
    const size_t gB0 = ((size_t)(n0 + wv * 32 + lr) << 8) + lperm * 8;
    const int ldsbase = wv * 2048;

    floatx4 acc[4][4];
    #pragma unroll
    for (int mi = 0; mi < 4; ++mi)
        #pragma unroll
        for (int ni = 0; ni < 4; ++ni)
            acc[mi][ni] = (floatx4){0.f, 0.f, 0.f, 0.f};

    for (int kb = 0; kb < 4; ++kb) {
        if (kb) __syncthreads();
        #pragma unroll
        for (int ca = 0; ca < 4; ++ca) {
            gl_lds16(Wb + gA0 + ca * 2048 + kb * 64, As + ldsbase + ca * 512);
            gl_lds16(Xb + gB0 + ca * 2048 + kb * 64, Bs + ldsbase + ca * 512);
        }
        __syncthreads();
        #pragma unroll
        for (int kk = 0; kk < 2; ++kk) {
            short8 af[4], bf[4];
            #pragma unroll
            for (int mi = 0; mi < 4; ++mi) {
                int row = wr * 64 + mi * 16 + c;
                int pos = (kk * 4 + q) ^ (c & 7);
                af[mi] = *(const short8*)&As[row * 64 + pos * 8];
            }
            #pragma unroll
            for (int ni = 0; ni < 4; ++ni) {
                int row = wc * 64 + ni * 16 + c;
                int pos = (kk * 4 + q) ^ (c & 7);
                bf[ni] = *(const short8*)&Bs[row * 64 + pos * 8];
            }
            #pragma unroll
            for (int mi = 0; mi < 4; ++mi)
                #pragma unroll
                for (int ni = 0; ni < 4; ++ni)
                    acc[mi][ni] = __builtin_amdgcn_mfma_f32_16x16x32_bf16(
                        af[mi], bf[ni], acc[mi][ni], 0, 0, 0);
        }
    }

    // Epilogue: D rows = codes (q*4+r), cols = queries (c).
    float4 s2v[4];
    #pragma unroll
    for (int mi = 0; mi < 4; ++mi)
        s2v[mi] = *(const float4*)&S2a[j0 + wr * 64 + mi * 16 + (q << 2)];

    #pragma unroll
    for (int ni = 0; ni < 4; ++ni) {
        float M1 = 0.f, M2 = 0.f; int I1 = 0;
        #pragma unroll
        for (int mi = 0; mi < 4; ++mi) {
            float v0 = fmaf(-2.f, acc[mi][ni][0], s2v[mi].x);
            float v1 = fmaf(-2.f, acc[mi][ni][1], s2v[mi].y);
            float v2 = fmaf(-2.f, acc[mi][ni][2], s2v[mi].z);
            float v3 = fmaf(-2.f, acc[mi][ni][3], s2v[mi].w);
            float lo01 = fminf(v0, v1), hi01 = fmaxf(v0, v1);
            float lo23 = fminf(v2, v3), hi23 = fmaxf(v2, v3);
            int i01 = v1 < v0 ? 1 : 0;
            int i23 = v3 < v2 ? 3 : 2;
            float m1 = fminf(lo01, lo23);
            float m2 = fminf(fmaxf(lo01, lo23), lo23 < lo01 ? hi23 : hi01);
            int idx = mi * 16 + (q << 2) + (lo23 < lo01 ? i23 : i01);
            if (mi == 0) { M1 = m1; M2 = m2; I1 = idx; }
            else {
                float nM2 = (m1 < M1) ? fminf(M1, m2) : fminf(M2, m1);
                I1 = (m1 < M1) ? idx : I1;   // ties keep earlier mi (lower idx)
                M1 = fminf(M1, m1);
                M2 = nM2;
            }
        }
        #pragma unroll
        for (int off = 16; off <= 32; off <<= 1) {
            float oM1 = __shfl_xor(M1, off);
            float oM2 = __shfl_xor(M2, off);
            int   oI1 = __shfl_xor(I1, off);
            float nM2 = fminf(fminf(M2, oM2), fmaxf(M1, oM1));
            bool take = (oM1 < M1) || (oM1 == M1 && oI1 < I1);  // first-index ties
            I1 = take ? oI1 : I1;
            M1 = fminf(M1, oM1);
            M2 = nM2;
        }
        if (q == 0) {
            ushort min16 = __builtin_bit_cast(ushort, (_Float16)M1);
            float delta = M2 - M1;
            ushort d16 = __builtin_bit_cast(ushort, (_Float16)delta);
            ushort d8 = d16 >> 8;
            float rec = (float)__builtin_bit_cast(_Float16, (ushort)(d8 << 8));
            if (rec > delta && d8) d8--;   // stored delta must be <= actual
            stg32[wc * 64 + ni * 16 + c][wr] =
                ((unsigned)min16 << 16) | ((unsigned)d8 << 8) | (unsigned)I1;
        }
    }
    __syncthreads();
    if (t < 128) {
        uint2 v = *(const uint2*)&stg32[t][0];
        *(uint2*)(bm32 + ((size_t)(n0 + t) << 8) + blockIdx.y * 2) = v;
    }
}

// ---------------------------------------------------------------------------
// ONE WAVE PER ROW. Scan 256 packed 64-code group entries (lane covers 4);
// candidates = group argmin for min<=thr, full 64 codes when min+delta<=thr
// (conservative superset). Exact np-fp32 sequential k-order FMA rescore,
// one candidate per lane, register-batched loads. Loss partial per row.
// ---------------------------------------------------------------------------
__global__ __launch_bounds__(256) void rescore8(const unsigned* __restrict__ bm32,
                                                const float* __restrict__ xf32,
                                                const float* __restrict__ w,
                                                const float* __restrict__ S2a,
                                                int* __restrict__ idxb,
                                                float* __restrict__ xcode,
                                                float* __restrict__ lpart) {
#pragma clang fp contract(off)
    __shared__ float xs[4][256];
    __shared__ short sing[4][128];
    __shared__ short blk[4][16];
    __shared__ int ns[4], nb[4];

    const int t = threadIdx.x, wv = t >> 6, l = t & 63;
    const int n = blockIdx.x * 4 + wv;
    if (l == 0) { ns[wv] = 0; nb[wv] = 0; }

    const float4 xv = *(const float4*)&xf32[((size_t)n << 8) + l * 4];
    *(float4*)&xs[wv][l * 4] = xv;

    // lane l covers group entries l*4 .. l*4+3 (16 B coalesced)
    const uint4 e = *(const uint4*)(bm32 + ((size_t)n << 8) + l * 4);
    unsigned ee[4] = {e.x, e.y, e.z, e.w};
    float vals[4];
    #pragma unroll
    for (int i = 0; i < 4; ++i)
        vals[i] = (float)__builtin_bit_cast(_Float16, (ushort)(ee[i] >> 16));
    float vmin = fminf(fminf(vals[0], vals[1]), fminf(vals[2], vals[3]));
    #pragma unroll
    for (int off = 1; off <= 32; off <<= 1) vmin = fminf(vmin, __shfl_xor(vmin, off));
    const float thr = vmin + MARGINF;
    #pragma unroll
    for (int i = 0; i < 4; ++i) {
        if (vals[i] <= thr) {
            const int jb = l * 4 + i;
            int p = atomicAdd(&ns[wv], 1);
            if (p < 128) sing[wv][p] = (short)(jb * 64 + (int)(ee[i] & 63u));
            float dr = (float)__builtin_bit_cast(_Float16,
                           (ushort)(((ee[i] >> 8) & 0xFFu) << 8));
            if (vals[i] + dr <= thr) {
                int pb = atomicAdd(&nb[wv], 1);
                if (pb < 16) blk[wv][pb] = (short)jb;
            }
        }
    }

    // exact np pairwise S1: lanes 0..15 (half h = l>>3, accumulator a = l&7)
    float racc = 0.f;
    if (l < 16) {
        const float* a_ = &xs[wv][(l >> 3) * 128];
        const int ai = l & 7;
        float v = a_[ai];
        racc = v * v;
        for (int i = 8; i < 128; i += 8) { v = a_[i + ai]; racc = racc + v * v; }
    }
    racc = racc + __shfl_xor(racc, 1);
    racc = racc + __shfl_xor(racc, 2);
    racc = racc + __shfl_xor(racc, 4);
    racc = racc + __shfl_xor(racc, 8);   // lane 0: hs0 + hs1 (np order)
    const float S1n = __shfl(racc, 0);

    const int nsv = ns[wv] < 128 ? ns[wv] : 128;
    const int nbv = nb[wv] < 16 ? nb[wv] : 16;
    const int ntot = nsv + nbv * 64;
    unsigned long long best = ~0ull;
    for (int s = l; s < ntot; s += 64) {
        const int j = (s < nsv)
            ? (int)sing[wv][s]
            : (int)blk[wv][(s - nsv) >> 6] * 64 + ((s - nsv) & 63);
        const float4* wr4 = (const float4*)(w + ((size_t)j << 8));
        float g = 0.f;
        #pragma unroll
        for (int half = 0; half < 4; ++half) {
            float4 buf[16];
            #pragma unroll
            for (int i = 0; i < 16; ++i) buf[i] = wr4[half * 16 + i];
            #pragma unroll
            for (int i = 0; i < 16; ++i) {   // sequential FMA in k-order (BLAS)
                const float4 xv4 = *(const float4*)&xs[wv][half * 64 + i * 4];
                g = fmaf(xv4.x, buf[i].x, g);
                g = fmaf(xv4.y, buf[i].y, g);
                g = fmaf(xv4.z, buf[i].z, g);
                g = fmaf(xv4.w, buf[i].w, g);
            }
        }
        float d = (S1n + S2a[j]) - 2.0f * g;
        unsigned long long key = ((unsigned long long)fsort(d) << 32) | (unsigned)j;
        if (key < best) best = key;
    }
    #pragma unroll
    for (int off = 1; off <= 32; off <<= 1) {
        unsigned long long o = __shfl_xor(best, off);
        if (o < best) best = o;
    }
    const int J = (int)(best & 0xffffffffu);

    // loss partial (w[J] L2-hot from the dot)
    const float4 wj = *(const float4*)&w[((size_t)J << 8) + l * 4];
    float d0 = wj.x - xv.x, d1 = wj.y - xv.y, d2 = wj.z - xv.z, d3 = wj.w - xv.w;
    float lacc = (d0 * d0 + d1 * d1) + (d2 * d2 + d3 * d3);
    #pragma unroll
    for (int off = 1; off <= 32; off <<= 1) lacc += __shfl_xor(lacc, off);
    if (l == 0) {
        idxb[n] = J;
        xcode[n] = (float)J;
        lpart[n] = lacc;
    }
}

// ---------------------------------------------------------------------------
// xq_img gather via 32x32 LDS transpose tiles: float4 row-chunk reads of
// w[id], 128B-coalesced writes to out. Block (0,0,0) also reduces loss.
// ---------------------------------------------------------------------------
__global__ __launch_bounds__(256) void outputs_k(const float* __restrict__ w,
                                                 const int* __restrict__ idxb,
                                                 const float* __restrict__ lpart,
                                                 float* __restrict__ out,
                                                 float* __restrict__ loss) {
    __shared__ float tile[32][33];
    __shared__ int ids[32];
    const int b = blockIdx.x, ht = blockIdx.y, ct = blockIdx.z;
    const int t = threadIdx.x;
    const int hw0 = ht * 32, c0 = ct * 32;
    if (t < 32) ids[t] = idxb[(b << 10) + hw0 + t];
    __syncthreads();
    {
        const int nl = t & 31, cq = t >> 5;
        float4 v = *(const float4*)&w[((size_t)ids[nl] << 8) + c0 + cq * 4];
        tile[nl][cq * 4]     = v.x;
        tile[nl][cq * 4 + 1] = v.y;
        tile[nl][cq * 4 + 2] = v.z;
        tile[nl][cq * 4 + 3] = v.w;
    }
    __syncthreads();
    {
        const int hwl = t & 31, cq = t >> 5;
        #pragma unroll
        for (int i = 0; i < 4; ++i) {
            const int cl = cq * 4 + i;
            out[((size_t)((b << 8) + c0 + cl) << 10) + hw0 + hwl] = tile[hwl][cl];
        }
    }
    if (b == 0 && ht == 0 && ct == 0) {
        __shared__ float red[256];
        float s = 0.f;
        for (int i = 0; i < 32; ++i) s += lpart[t + (i << 8)];
        red[t] = s;
        __syncthreads();
        for (int k = 128; k > 0; k >>= 1) {
            if (t < k) red[t] += red[t + k];
            __syncthreads();
        }
        if (t == 0) *loss = red[0] * (1.25f / 2097152.0f);
    }
}

// ---------------------------------------------------------------------------
extern "C" void kernel_launch(void* const* d_in, const int* in_sizes, int n_in,
                              void* d_out, int out_size, void* d_ws, size_t ws_size,
                              hipStream_t stream) {
    const float* x = (const float*)d_in[0];
    const float* w = (const float*)d_in[1];
    float* out = (float*)d_out;

    char* ws = (char*)d_ws;
    const size_t MB = 1024u * 1024u;
    ushort*   xbf   = (ushort*)  (ws);                   //  4 MiB
    float*    xf32  = (float*)   (ws + 4 * MB);          //  8 MiB
    ushort*   wbf   = (ushort*)  (ws + 12 * MB);         //  8 MiB
    float*    S2a   = (float*)   (ws + 20 * MB);         // 64 KiB
    unsigned* bm32  = (unsigned*)(ws + 21 * MB);         //  8 MiB
    int*      idxb  = (int*)     (ws + 29 * MB);         // 32 KiB
    float*    lpart = (float*)   (ws + 29 * MB + 65536); // 32 KiB

    float* loss_ptr  = out + 2097152;
    float* xcode_ptr = out + 2097153;

    prep_all<<<dim3(3072),      256, 0, stream>>>(x, w, xf32, xbf, wbf, S2a);
    gemm_min<<<dim3(64, 128),   256, 0, stream>>>(wbf, xbf, S2a, bm32);
    rescore8<<<dim3(2048),      256, 0, stream>>>(bm32, xf32, w, S2a, idxb,
                                                  xcode_ptr, lpart);
    outputs_k<<<dim3(8, 32, 8), 256, 0, stream>>>(w, idxb, lpart, out, loss_ptr);
}